// Round 7
// baseline (255.683 us; speedup 1.0000x reference)
//
#include <hip/hip_runtime.h>
#include <stdint.h>

// graphConv: out[b] = (sum_k W_k S^k) @ X_b ; B=128, N=1024, D=64, K=8
//
// All-fp16 tree (fp32 MFMA accumulate), 32x32x16 MFMA.
//   prep: S (rm+cm), W1,W3,W5,W7 (rm) -> fp16 ; XT[b*64+d][k] = X[b][k][d]
//   L1: S2 = S*S (rm+cm) ; U_j = W_{2j}(fp32 add) + W_{2j+1}*S  [5 jobs]
//   L2: S4 = S2*S2 (cm) ; V0 = U0 + U1*S2 ; V1 = U2 + U3*S2     [3 jobs]
//   L3: P = V1*S4, split-K=4 fp32 partials (non-atomic)
//   combine: A = V0 + sum P
//   apply: out[b] = A @ X_b  (128n x 64d x batch blocks, XCD=b%8)
//
// LDS layout = FRAGMENT-LINEAR (fixes R6's 4-cyc/read bank conflicts):
// 32-row block j, k-slice ks lives at lds + j*4096B + ks*1024B + lane*16B.
// DMA writes and frag reads are both lane-consecutive -> 0 conflicts.

#define NN 1024
#define NBATCH 128
#define DDIM 64

typedef float floatx16 __attribute__((ext_vector_type(16)));
typedef _Float16 f16x8 __attribute__((ext_vector_type(8)));
typedef unsigned short u16;

__device__ __forceinline__ u16 f2h(float f) {
  union { _Float16 h; u16 u; } v; v.h = (_Float16)f; return v.u;
}
__device__ __forceinline__ float h2f(u16 u) {
  union { _Float16 h; u16 u; } v; v.u = u; return (float)v.h;
}

__device__ __forceinline__ void gll16(const void* g, void* l) {
  __builtin_amdgcn_global_load_lds(
      (const __attribute__((address_space(1))) void*)g,
      (__attribute__((address_space(3))) void*)l, 16, 0, 0);
}

// Stage ROWSx64 u16 tile (row stride NN) in fragment-linear order.
// Op (j,ks): lane l fetches global row j*32+(l&31), 16B chunk ks*2+(l>>5)
// -> lds u16 offset j*2048 + ks*512 (+ lane*16B by HW).
template <int ROWS>
__device__ __forceinline__ void stageF(const u16* __restrict__ g, u16* lds,
                                       int wave, int lane) {
  const int r = lane & 31, h = lane >> 5;
#pragma unroll
  for (int i = 0; i < ROWS / 32; ++i) {
    const int o = wave + i * 4;          // op 0..ROWS/8-1
    const int j = o >> 2, ks = o & 3;
    gll16(g + (size_t)(j * 32 + r) * NN + (ks * 2 + h) * 8,
          lds + j * 2048 + ks * 512);
  }
}

// Fragment read: 32-row block j, k-slice ks -> lane-consecutive 16B.
__device__ __forceinline__ f16x8 fragF(const u16* lds, int j, int ks, int lane) {
  return *(const f16x8*)&lds[j * 2048 + ks * 512 + lane * 8];
}

// ---------------- prep: fp32->fp16 converts + X transpose ------------------
struct CvtJob { const float* src; u16* rm; u16* cm; };
struct PrepArgs { CvtJob cv[5]; const float* X; u16* XT; };

__global__ __launch_bounds__(256) void prep_kernel(PrepArgs pa) {
  const int z = blockIdx.z, x = blockIdx.x, t = threadIdx.x;
  if (z < 5) {
    if (x >= NN * NN / 1024) return;
    CvtJob jb = pa.cv[z];
    int idx4 = x * 256 + t;
    int e = idx4 * 4;
    int row = e >> 10, col = e & (NN - 1);
    float4 f = ((const float4*)jb.src)[idx4];
    u16 h[4] = { f2h(f.x), f2h(f.y), f2h(f.z), f2h(f.w) };
    uint2 p;
    p.x = (uint32_t)h[0] | ((uint32_t)h[1] << 16);
    p.y = (uint32_t)h[2] | ((uint32_t)h[3] << 16);
    *(uint2*)&jb.rm[e] = p;
    if (jb.cm) {
#pragma unroll
      for (int i = 0; i < 4; ++i) jb.cm[(size_t)(col + i) * NN + row] = h[i];
    }
    return;
  }
  // transpose: x in [0, 16*NBATCH)
  __shared__ u16 T[64][72];
  const int k0 = (x & 15) * 64, b = x >> 4;
#pragma unroll
  for (int it = 0; it < 4; ++it) {
    int kr = (t >> 4) + it * 16;
    int d4 = (t & 15) * 4;
    float4 f = *(const float4*)&pa.X[((size_t)b * NN + k0 + kr) * DDIM + d4];
    T[d4 + 0][kr] = f2h(f.x);
    T[d4 + 1][kr] = f2h(f.y);
    T[d4 + 2][kr] = f2h(f.z);
    T[d4 + 3][kr] = f2h(f.w);
  }
  __syncthreads();
#pragma unroll
  for (int it = 0; it < 2; ++it) {
    int d = (t >> 3) + it * 32;
    int kc = (t & 7) * 8;
    *(uint4*)&pa.XT[((size_t)b * DDIM + d) * NN + k0 + kc] = *(uint4*)&T[d][kc];
  }
}

// ---------------- fp16 GEMM (32x32x16): out = [add +] A*B ------------------
struct GemmJob {
  const u16* A;        // fp16 row-major MxK
  const u16* B;        // fp16 col-major: (k,n) at [n*NN+k]
  const float* addF;   // optional fp32 additive (row-major)
  const u16* addH;     // optional fp16 additive (row-major)
  u16* outRm;          // optional fp16 row-major out
  u16* outCm;          // optional fp16 col-major out
  float* outP;         // split-K fp32 partials (KSPLIT>1 path)
};
struct GemmJobs { GemmJob j[5]; };

template <int BM, int BN, int KSPLIT>
__global__ __launch_bounds__(256) void gemm_f16(GemmJobs jobs) {
  const GemmJob jb = jobs.j[blockIdx.z / KSPLIT];
  const int chunk = blockIdx.z % KSPLIT;
  __shared__ u16 As[BM * 64], Bs[BN * 64];
  const int t = threadIdx.x, wave = t >> 6, lane = t & 63;
  const int wm = wave >> 1, wn = wave & 1;
  const int l31 = lane & 31, half = lane >> 5;
  const int bm = blockIdx.x * BM, bn = blockIdx.y * BN;
  constexpr int MI = BM / 64, NI = BN / 64, KTPB = 16 / KSPLIT;
  floatx16 acc[MI][NI] = {};

  for (int kk = 0; kk < KTPB; ++kk) {
    const int kt = chunk * KTPB + kk;
    __syncthreads();
    stageF<BM>(jb.A + (size_t)bm * NN + kt * 64, As, wave, lane);
    stageF<BN>(jb.B + (size_t)bn * NN + kt * 64, Bs, wave, lane);
    __syncthreads();
#pragma unroll
    for (int ks = 0; ks < 4; ++ks) {
      f16x8 bf[NI];
#pragma unroll
      for (int ni = 0; ni < NI; ++ni)
        bf[ni] = fragF(Bs, wn * (BN / 64) + ni, ks, lane);
#pragma unroll
      for (int mi = 0; mi < MI; ++mi) {
        f16x8 a = fragF(As, wm * (BM / 64) + mi, ks, lane);
#pragma unroll
        for (int ni = 0; ni < NI; ++ni)
          acc[mi][ni] = __builtin_amdgcn_mfma_f32_32x32x16_f16(a, bf[ni], acc[mi][ni], 0, 0, 0);
      }
    }
  }

#pragma unroll
  for (int mi = 0; mi < MI; ++mi)
#pragma unroll
    for (int ni = 0; ni < NI; ++ni)
#pragma unroll
      for (int r = 0; r < 16; ++r) {
        int row = bm + wm * (BM / 2) + mi * 32 + (r & 3) + 8 * (r >> 2) + 4 * half;
        int col = bn + wn * (BN / 2) + ni * 32 + l31;
        size_t rm = (size_t)row * NN + col;
        float v = acc[mi][ni][r];
        if (KSPLIT > 1) {
          jb.outP[(size_t)chunk * NN * NN + rm] = v;
        } else {
          if (jb.addF) v += jb.addF[rm];
          if (jb.addH) v += h2f(jb.addH[rm]);
          u16 h = f2h(v);
          if (jb.outRm) jb.outRm[rm] = h;
          if (jb.outCm) jb.outCm[(size_t)col * NN + row] = h;
        }
      }
}

// ---------------- combine: A = V0 + sum_z P --------------------------------
__global__ __launch_bounds__(256) void combine_A(const float* __restrict__ parts,
                                                 const u16* __restrict__ v0,
                                                 u16* __restrict__ A) {
  int e = (blockIdx.x * 256 + threadIdx.x) * 4;
  float4 s = *(const float4*)&parts[e];
#pragma unroll
  for (int z = 1; z < 4; ++z) {
    float4 p = *(const float4*)&parts[(size_t)z * NN * NN + e];
    s.x += p.x; s.y += p.y; s.z += p.z; s.w += p.w;
  }
  uint2 h = *(const uint2*)&v0[e];
  uint2 o;
  o.x = (uint32_t)f2h(s.x + h2f((u16)h.x)) |
        ((uint32_t)f2h(s.y + h2f((u16)(h.x >> 16))) << 16);
  o.y = (uint32_t)f2h(s.z + h2f((u16)h.y)) |
        ((uint32_t)f2h(s.w + h2f((u16)(h.y >> 16))) << 16);
  *(uint2*)&A[e] = o;
}

// ---------------- apply: out[b][n][d] = A @ X_b (32x32x16) -----------------
__global__ __launch_bounds__(256) void apply_gemm(const u16* __restrict__ A,
                                                  const u16* __restrict__ XT,
                                                  float* __restrict__ out) {
  __shared__ u16 As[8192], Xs[4096];  // 16 KB + 8 KB
  const int t = threadIdx.x, wave = t >> 6, lane = t & 63;
  const int l31 = lane & 31, half = lane >> 5;
  const int b = blockIdx.x, bm = blockIdx.y * 128;
  floatx16 acc[2] = {};

  for (int kt = 0; kt < 16; ++kt) {
    __syncthreads();
    stageF<128>(A + (size_t)bm * NN + kt * 64, As, wave, lane);
    stageF<64>(XT + (size_t)b * DDIM * NN + kt * 64, Xs, wave, lane);
    __syncthreads();
#pragma unroll
    for (int ks = 0; ks < 4; ++ks) {
      f16x8 a = fragF(As, wave, ks, lane);
#pragma unroll
      for (int ni = 0; ni < 2; ++ni) {
        f16x8 x = fragF(Xs, ni, ks, lane);
        acc[ni] = __builtin_amdgcn_mfma_f32_32x32x16_f16(a, x, acc[ni], 0, 0, 0);
      }
    }
  }

#pragma unroll
  for (int ni = 0; ni < 2; ++ni)
#pragma unroll
    for (int r = 0; r < 16; ++r) {
      int row = bm + wave * 32 + (r & 3) + 8 * (r >> 2) + 4 * half;
      int d = ni * 32 + l31;
      out[((size_t)b * NN + row) * DDIM + d] = acc[ni][r];
    }
}

extern "C" void kernel_launch(void* const* d_in, const int* in_sizes, int n_in,
                              void* d_out, int out_size, void* d_ws, size_t ws_size,
                              hipStream_t stream) {
  const float* nodes  = (const float*)d_in[0];  // [128,1024,64]
  const float* weight = (const float*)d_in[1];  // [8,1024,1024]
  const float* gs     = (const float*)d_in[2];  // [1024,1024]
  float* out = (float*)d_out;
  u16* ws = (u16*)d_ws;
  const size_t MB = (size_t)NN * NN;
  auto buf = [&](int i) -> u16* { return ws + (size_t)i * MB; };
  // 2MB fp16 slots: 0 S rm | 1 S cm | 2..5 W1,3,5,7 rm | 6 S2 rm | 7 S2 cm
  // 8..11 U0..U3 | 12 S4 cm | 13 V0 | 14 V1 | 15 A | 16..23 XT (16 MB)
  // 24..31 L3 fp32 partials (16 MB). Total 64 MB.

  u16* XT = buf(16);
  PrepArgs pa{};
  pa.cv[0] = { gs,              buf(0), buf(1) };
  pa.cv[1] = { weight + 1 * MB, buf(2), nullptr };
  pa.cv[2] = { weight + 3 * MB, buf(3), nullptr };
  pa.cv[3] = { weight + 5 * MB, buf(4), nullptr };
  pa.cv[4] = { weight + 7 * MB, buf(5), nullptr };
  pa.X = nodes; pa.XT = XT;
  prep_kernel<<<dim3(16 * NBATCH, 1, 6), 256, 0, stream>>>(pa);

  // L1: S2 = S*S ; U_j = W_{2j} + W_{2j+1}*S
  GemmJobs g1{};
  g1.j[0] = { buf(0), buf(1), nullptr,         nullptr, buf(6),  buf(7),  nullptr };
  g1.j[1] = { buf(2), buf(1), weight + 0 * MB, nullptr, buf(8),  nullptr, nullptr };
  g1.j[2] = { buf(3), buf(1), weight + 2 * MB, nullptr, buf(9),  nullptr, nullptr };
  g1.j[3] = { buf(4), buf(1), weight + 4 * MB, nullptr, buf(10), nullptr, nullptr };
  g1.j[4] = { buf(5), buf(1), weight + 6 * MB, nullptr, buf(11), nullptr, nullptr };
  gemm_f16<64, 128, 1><<<dim3(16, 8, 5), 256, 0, stream>>>(g1);

  // L2: S4 = S2*S2 (cm) ; V0 = U0 + U1*S2 ; V1 = U2 + U3*S2
  GemmJobs g2{};
  g2.j[0] = { buf(6),  buf(7), nullptr, nullptr, nullptr, buf(12), nullptr };
  g2.j[1] = { buf(9),  buf(7), nullptr, buf(8),  buf(13), nullptr, nullptr };
  g2.j[2] = { buf(11), buf(7), nullptr, buf(10), buf(14), nullptr, nullptr };
  gemm_f16<64, 64, 1><<<dim3(16, 16, 3), 256, 0, stream>>>(g2);

  // L3: P = V1*S4, split-K=4 non-atomic partials
  float* parts = (float*)buf(24);
  GemmJobs g3{};
  g3.j[0] = { buf(14), buf(12), nullptr, nullptr, nullptr, nullptr, parts };
  gemm_f16<64, 64, 4><<<dim3(16, 16, 4), 256, 0, stream>>>(g3);

  // A = V0 + sum P
  combine_A<<<dim3(NN * NN / 1024), 256, 0, stream>>>(parts, buf(13), buf(15));

  apply_gemm<<<dim3(NBATCH, 8), 256, 0, stream>>>(buf(15), XT, out);
}

// Round 8
// 207.922 us; speedup vs baseline: 1.2297x; 1.2297x over previous
//
#include <hip/hip_runtime.h>
#include <stdint.h>

// graphConv: out[b] = (sum_k W_k S^k) @ X_b ; B=128, N=1024, D=64, K=8
//
// All-fp16 tree (fp32 MFMA accumulate), 32x32x16 MFMA.
//   prep: S (rm+cm), W1,W3,W5,W7 (rm) -> fp16 TILED ; XT tiled
//   L1: S2 = S*S (rm+cm) ; U_j = W_{2j}(fp32 add) + W_{2j+1}*S  [5 jobs]
//   L2: S4 = S2*S2 (cm) ; V0 = U0 + U1*S2 ; V1 = U2 + U3*S2     [3 jobs]
//   L3: P = V1*S4, split-K=4 fp32 partials (non-atomic)
//   combine: A = V0 + sum P (tiled)
//   apply: out[b] = A @ X_b  (128n x 64d x batch blocks, XCD=b%8)
//
// TILED global layout for all fp16 operands: (row,col) at
//   ((row>>5)*128 + (col>>3))*256 + (row&31)*8 + (col&7)
// -> each global_load_lds wave-op reads 1KB CONTIGUOUS (lane*16B) and lands
// lane-consecutive in LDS (fragment-linear): 0 bank conflicts (R7-verified)
// AND ideal coalescing (fixes R7's 32-way row scatter).

#define NN 1024
#define NBATCH 128
#define DDIM 64

typedef float floatx16 __attribute__((ext_vector_type(16)));
typedef _Float16 f16x8 __attribute__((ext_vector_type(8)));
typedef unsigned short u16;

__device__ __forceinline__ u16 f2h(float f) {
  union { _Float16 h; u16 u; } v; v.h = (_Float16)f; return v.u;
}
__device__ __forceinline__ float h2f(u16 u) {
  union { _Float16 h; u16 u; } v; v.u = u; return (float)v.h;
}

// tiled element offset (cols always 1024 wide)
__device__ __forceinline__ size_t tix(int row, int col) {
  return ((size_t)((row >> 5) * 128 + (col >> 3)) * 32 + (row & 31)) * 8 + (col & 7);
}

__device__ __forceinline__ void gll16(const void* g, void* l) {
  __builtin_amdgcn_global_load_lds(
      (const __attribute__((address_space(1))) void*)g,
      (__attribute__((address_space(3))) void*)l, 16, 0, 0);
}

// Stage ROWSx64 (fp16) window from TILED global: row-block rb0+j, k-chunks
// kc0..kc0+7. Wave-op (j,ks): 1KB contiguous at lane*16B -> fragment-linear
// LDS at j*4KB + ks*1KB + lane*16B. Both sides perfect.
template <int ROWS>
__device__ __forceinline__ void stageT(const u16* __restrict__ g, int rb0,
                                       int kc0, u16* lds, int wave, int lane) {
#pragma unroll
  for (int i = 0; i < ROWS / 32; ++i) {
    const int o = wave + i * 4;
    const int j = o >> 2, ks = o & 3;
    gll16(g + ((size_t)(rb0 + j) * 128 + kc0 + ks * 2) * 256 + lane * 8,
          lds + j * 2048 + ks * 512);
  }
}

// Fragment read: 32-row block j, k-slice ks -> lane-consecutive 16B.
__device__ __forceinline__ f16x8 fragF(const u16* lds, int j, int ks, int lane) {
  return *(const f16x8*)&lds[j * 2048 + ks * 512 + lane * 8];
}

// ---------------- prep: fp32->fp16 tiled converts + X transpose ------------
struct CvtJob { const float* src; u16* rm; u16* cm; };
struct PrepArgs { CvtJob cv[5]; const float* X; u16* XT; };

__global__ __launch_bounds__(256) void prep_kernel(PrepArgs pa) {
  const int z = blockIdx.z, x = blockIdx.x, t = threadIdx.x;
  if (z < 5) {
    if (x >= NN * NN / 1024) return;
    CvtJob jb = pa.cv[z];
    int idx4 = x * 256 + t;
    int e = idx4 * 4;
    int row = e >> 10, col = e & (NN - 1);
    float4 f = ((const float4*)jb.src)[idx4];
    u16 h[4] = { f2h(f.x), f2h(f.y), f2h(f.z), f2h(f.w) };
    uint2 p;
    p.x = (uint32_t)h[0] | ((uint32_t)h[1] << 16);
    p.y = (uint32_t)h[2] | ((uint32_t)h[3] << 16);
    *(uint2*)&jb.rm[tix(row, col)] = p;   // col%4==0 -> 4 consec u16 in chunk
    if (jb.cm) {
#pragma unroll
      for (int i = 0; i < 4; ++i) jb.cm[tix(col + i, row)] = h[i];
    }
    return;
  }
  // transpose: x in [0, 16*NBATCH)
  __shared__ u16 T[64][72];
  const int k0 = (x & 15) * 64, b = x >> 4;
#pragma unroll
  for (int it = 0; it < 4; ++it) {
    int kr = (t >> 4) + it * 16;
    int d4 = (t & 15) * 4;
    float4 f = *(const float4*)&pa.X[((size_t)b * NN + k0 + kr) * DDIM + d4];
    T[d4 + 0][kr] = f2h(f.x);
    T[d4 + 1][kr] = f2h(f.y);
    T[d4 + 2][kr] = f2h(f.z);
    T[d4 + 3][kr] = f2h(f.w);
  }
  __syncthreads();
#pragma unroll
  for (int it = 0; it < 2; ++it) {
    int d = (t >> 3) + it * 32;
    int kc = (t & 7) * 8;
    *(uint4*)&pa.XT[tix(b * DDIM + d, k0 + kc)] = *(uint4*)&T[d][kc];
  }
}

// ---------------- fp16 GEMM (32x32x16): out = [add +] A*B ------------------
struct GemmJob {
  const u16* A;        // fp16 TILED MxK
  const u16* B;        // fp16 TILED B^T (rows = n)
  const float* addF;   // optional fp32 additive (natural row-major)
  const u16* addH;     // optional fp16 additive (tiled)
  u16* outRm;          // optional fp16 tiled out
  u16* outCm;          // optional fp16 tiled transposed out
  float* outP;         // split-K fp32 partials, natural (KSPLIT>1)
};
struct GemmJobs { GemmJob j[5]; };

template <int BM, int BN, int KSPLIT>
__global__ __launch_bounds__(256) void gemm_f16(GemmJobs jobs) {
  const GemmJob jb = jobs.j[blockIdx.z / KSPLIT];
  const int chunk = blockIdx.z % KSPLIT;
  __shared__ u16 As[BM * 64], Bs[BN * 64];
  const int t = threadIdx.x, wave = t >> 6, lane = t & 63;
  const int wm = wave >> 1, wn = wave & 1;
  const int l31 = lane & 31, half = lane >> 5;
  const int bm = blockIdx.x * BM, bn = blockIdx.y * BN;
  constexpr int MI = BM / 64, NI = BN / 64, KTPB = 16 / KSPLIT;
  floatx16 acc[MI][NI] = {};

  for (int kk = 0; kk < KTPB; ++kk) {
    const int kt = chunk * KTPB + kk;
    __syncthreads();
    stageT<BM>(jb.A, bm >> 5, kt * 8, As, wave, lane);
    stageT<BN>(jb.B, bn >> 5, kt * 8, Bs, wave, lane);
    __syncthreads();
#pragma unroll
    for (int ks = 0; ks < 4; ++ks) {
      f16x8 bf[NI];
#pragma unroll
      for (int ni = 0; ni < NI; ++ni)
        bf[ni] = fragF(Bs, wn * NI + ni, ks, lane);
#pragma unroll
      for (int mi = 0; mi < MI; ++mi) {
        f16x8 a = fragF(As, wm * MI + mi, ks, lane);
#pragma unroll
        for (int ni = 0; ni < NI; ++ni)
          acc[mi][ni] = __builtin_amdgcn_mfma_f32_32x32x16_f16(a, bf[ni], acc[mi][ni], 0, 0, 0);
      }
    }
  }

#pragma unroll
  for (int mi = 0; mi < MI; ++mi)
#pragma unroll
    for (int ni = 0; ni < NI; ++ni)
#pragma unroll
      for (int r = 0; r < 16; ++r) {
        int row = bm + wm * (BM / 2) + mi * 32 + (r & 3) + 8 * (r >> 2) + 4 * half;
        int col = bn + wn * (BN / 2) + ni * 32 + l31;
        float v = acc[mi][ni][r];
        if (KSPLIT > 1) {
          jb.outP[(size_t)chunk * NN * NN + (size_t)row * NN + col] = v;
        } else {
          if (jb.addF) v += jb.addF[(size_t)row * NN + col];
          if (jb.addH) v += h2f(jb.addH[tix(row, col)]);
          u16 h = f2h(v);
          if (jb.outRm) jb.outRm[tix(row, col)] = h;
          if (jb.outCm) jb.outCm[tix(col, row)] = h;
        }
      }
}

// ---------------- combine: A = V0 + sum_z P (tiled out) --------------------
__global__ __launch_bounds__(256) void combine_A(const float* __restrict__ parts,
                                                 const u16* __restrict__ v0,
                                                 u16* __restrict__ A) {
  int e = (blockIdx.x * 256 + threadIdx.x) * 4;  // tiled-linear offset
  int row = ((e >> 3) & 31) + (e >> 15) * 32;
  int col = (((e >> 8) & 127) * 8) + (e & 7);
  size_t nat = (size_t)row * NN + col;
  float4 s = *(const float4*)&parts[nat];
#pragma unroll
  for (int z = 1; z < 4; ++z) {
    float4 p = *(const float4*)&parts[(size_t)z * NN * NN + nat];
    s.x += p.x; s.y += p.y; s.z += p.z; s.w += p.w;
  }
  uint2 h = *(const uint2*)&v0[e];
  uint2 o;
  o.x = (uint32_t)f2h(s.x + h2f((u16)h.x)) |
        ((uint32_t)f2h(s.y + h2f((u16)(h.x >> 16))) << 16);
  o.y = (uint32_t)f2h(s.z + h2f((u16)h.y)) |
        ((uint32_t)f2h(s.w + h2f((u16)(h.y >> 16))) << 16);
  *(uint2*)&A[e] = o;
}

// ---------------- apply: out[b][n][d] = A @ X_b (32x32x16) -----------------
__global__ __launch_bounds__(256) void apply_gemm(const u16* __restrict__ A,
                                                  const u16* __restrict__ XT,
                                                  float* __restrict__ out) {
  __shared__ u16 As[8192], Xs[4096];  // 16 KB + 8 KB
  const int t = threadIdx.x, wave = t >> 6, lane = t & 63;
  const int l31 = lane & 31, half = lane >> 5;
  const int b = blockIdx.x, bm = blockIdx.y * 128;
  floatx16 acc[2] = {};

  for (int kt = 0; kt < 16; ++kt) {
    __syncthreads();
    stageT<128>(A, bm >> 5, kt * 8, As, wave, lane);
    stageT<64>(XT, b * 2, kt * 8, Xs, wave, lane);
    __syncthreads();
#pragma unroll
    for (int ks = 0; ks < 4; ++ks) {
      f16x8 a = fragF(As, wave, ks, lane);
#pragma unroll
      for (int ni = 0; ni < 2; ++ni) {
        f16x8 x = fragF(Xs, ni, ks, lane);
        acc[ni] = __builtin_amdgcn_mfma_f32_32x32x16_f16(a, x, acc[ni], 0, 0, 0);
      }
    }
  }

#pragma unroll
  for (int ni = 0; ni < 2; ++ni)
#pragma unroll
    for (int r = 0; r < 16; ++r) {
      int row = bm + wave * 32 + (r & 3) + 8 * (r >> 2) + 4 * half;
      int d = ni * 32 + l31;
      out[((size_t)b * NN + row) * DDIM + d] = acc[ni][r];
    }
}

extern "C" void kernel_launch(void* const* d_in, const int* in_sizes, int n_in,
                              void* d_out, int out_size, void* d_ws, size_t ws_size,
                              hipStream_t stream) {
  const float* nodes  = (const float*)d_in[0];  // [128,1024,64]
  const float* weight = (const float*)d_in[1];  // [8,1024,1024]
  const float* gs     = (const float*)d_in[2];  // [1024,1024]
  float* out = (float*)d_out;
  u16* ws = (u16*)d_ws;
  const size_t MB = (size_t)NN * NN;
  auto buf = [&](int i) -> u16* { return ws + (size_t)i * MB; };
  // 2MB fp16 tiled slots: 0 S | 1 S^T | 2..5 W1,3,5,7 | 6 S2 | 7 S2^T
  // 8..11 U0..U3 | 12 S4^T | 13 V0 | 14 V1 | 15 A | 16..23 XT (16 MB)
  // 24..31 L3 fp32 partials (16 MB). Total 64 MB.

  u16* XT = buf(16);
  PrepArgs pa{};
  pa.cv[0] = { gs,              buf(0), buf(1) };
  pa.cv[1] = { weight + 1 * MB, buf(2), nullptr };
  pa.cv[2] = { weight + 3 * MB, buf(3), nullptr };
  pa.cv[3] = { weight + 5 * MB, buf(4), nullptr };
  pa.cv[4] = { weight + 7 * MB, buf(5), nullptr };
  pa.X = nodes; pa.XT = XT;
  prep_kernel<<<dim3(16 * NBATCH, 1, 6), 256, 0, stream>>>(pa);

  // L1: S2 = S*S ; U_j = W_{2j} + W_{2j+1}*S
  GemmJobs g1{};
  g1.j[0] = { buf(0), buf(1), nullptr,         nullptr, buf(6),  buf(7),  nullptr };
  g1.j[1] = { buf(2), buf(1), weight + 0 * MB, nullptr, buf(8),  nullptr, nullptr };
  g1.j[2] = { buf(3), buf(1), weight + 2 * MB, nullptr, buf(9),  nullptr, nullptr };
  g1.j[3] = { buf(4), buf(1), weight + 4 * MB, nullptr, buf(10), nullptr, nullptr };
  g1.j[4] = { buf(5), buf(1), weight + 6 * MB, nullptr, buf(11), nullptr, nullptr };
  gemm_f16<64, 128, 1><<<dim3(16, 8, 5), 256, 0, stream>>>(g1);

  // L2: S4 = S2*S2 (cm) ; V0 = U0 + U1*S2 ; V1 = U2 + U3*S2
  GemmJobs g2{};
  g2.j[0] = { buf(6),  buf(7), nullptr, nullptr, nullptr, buf(12), nullptr };
  g2.j[1] = { buf(9),  buf(7), nullptr, buf(8),  buf(13), nullptr, nullptr };
  g2.j[2] = { buf(11), buf(7), nullptr, buf(10), buf(14), nullptr, nullptr };
  gemm_f16<64, 64, 1><<<dim3(16, 16, 3), 256, 0, stream>>>(g2);

  // L3: P = V1*S4, split-K=4 non-atomic partials
  float* parts = (float*)buf(24);
  GemmJobs g3{};
  g3.j[0] = { buf(14), buf(12), nullptr, nullptr, nullptr, nullptr, parts };
  gemm_f16<64, 64, 4><<<dim3(16, 16, 4), 256, 0, stream>>>(g3);

  // A = V0 + sum P
  combine_A<<<dim3(NN * NN / 1024), 256, 0, stream>>>(parts, buf(13), buf(15));

  apply_gemm<<<dim3(NBATCH, 8), 256, 0, stream>>>(buf(15), XT, out);
}